// Round 1
// baseline (893.208 us; speedup 1.0000x reference)
//
#include <hip/hip_runtime.h>

// ---------------------------------------------------------------------------
// GAT edge-average layer, MI355X.
// Phase 1a: T[n][c] = x[n] . W'[c]   (c<128: Wf[c][k]; c>=128: Wf[c-128][128+k])
// Phase 1b: p[n] = x[n].w1, q[n] = x[n].w2  (fp64)
// Phase 2 : per edge e: y = relu(U[src]+V[tgt]+bf); a = p[src]+q[tgt]+bw (f64)
//           atomic scatter: out[tgt] += y*a (f32), den[tgt] += a (f64)
// Phase 3 : out[n][j] /= (den[n] + 1e-6)
// ---------------------------------------------------------------------------

__global__ __launch_bounds__(256) void k_node_transform(
    const float* __restrict__ x, const float* __restrict__ Wf,
    float* __restrict__ T, int N)
{
    // 64-node x 64-col tile, K=128 fully resident. XOR-swizzled LDS (no pad;
    // 64KB total -> 2 blocks/CU).
    __shared__ float xs[64][128];
    __shared__ float ws[64][128];
    const int t  = threadIdx.x;
    const int n0 = blockIdx.x * 64;
    const int c0 = blockIdx.y * 64;   // col tile: 0,64,128,192

    // stage x tile (rows n0..n0+63, all 128 k), swizzle float4 slot by row&7
    #pragma unroll
    for (int i = 0; i < 8; ++i) {
        int idx = t + i * 256;          // 0..2047 float4 slots
        int row = idx >> 5;
        int c4  = idx & 31;
        int n = n0 + row;
        float4 v = make_float4(0.f, 0.f, 0.f, 0.f);
        if (n < N) v = *(const float4*)(x + (size_t)n * 128 + c4 * 4);
        *(float4*)(&xs[row][(c4 ^ (row & 7)) * 4]) = v;
    }
    // stage W' tile (cols c0..c0+63)
    #pragma unroll
    for (int i = 0; i < 8; ++i) {
        int idx = t + i * 256;
        int row = idx >> 5;             // col within tile
        int c4  = idx & 31;
        int c = c0 + row;
        const float* wsrc = (c < 128) ? (Wf + (size_t)c * 256 + c4 * 4)
                                      : (Wf + (size_t)(c - 128) * 256 + 128 + c4 * 4);
        *(float4*)(&ws[row][(c4 ^ (row & 7)) * 4]) = *(const float4*)wsrc;
    }
    __syncthreads();

    const int tx = t & 15, ty = t >> 4;
    // thread covers nodes n0 + 4*ty + i (i<4), cols c0 + tx + 16*j (j<4)
    float acc[4][4] = {};
    #pragma unroll 8
    for (int k4 = 0; k4 < 32; ++k4) {
        float4 xv[4], wv[4];
        #pragma unroll
        for (int i = 0; i < 4; ++i) {
            int r = ty * 4 + i;
            xv[i] = *(const float4*)(&xs[r][(k4 ^ (r & 7)) * 4]);
        }
        #pragma unroll
        for (int j = 0; j < 4; ++j) {
            int r = tx + 16 * j;
            wv[j] = *(const float4*)(&ws[r][(k4 ^ (r & 7)) * 4]);
        }
        #pragma unroll
        for (int i = 0; i < 4; ++i)
            #pragma unroll
            for (int j = 0; j < 4; ++j)
                acc[i][j] += xv[i].x * wv[j].x + xv[i].y * wv[j].y
                           + xv[i].z * wv[j].z + xv[i].w * wv[j].w;
    }

    #pragma unroll
    for (int i = 0; i < 4; ++i) {
        int n = n0 + ty * 4 + i;
        if (n < N) {
            float* Trow = T + (size_t)n * 256 + c0;
            #pragma unroll
            for (int j = 0; j < 4; ++j)
                Trow[tx + 16 * j] = acc[i][j];
        }
    }
}

__global__ __launch_bounds__(256) void k_pq(
    const float* __restrict__ x, const float* __restrict__ Ww,
    double* __restrict__ p, double* __restrict__ q, int N)
{
    int wid  = (blockIdx.x * 256 + threadIdx.x) >> 6;   // one wave per node
    int lane = threadIdx.x & 63;
    if (wid >= N) return;
    const float* xr = x + (size_t)wid * 128;
    float x0 = xr[lane], x1 = xr[64 + lane];
    double ps = (double)x0 * (double)Ww[lane]       + (double)x1 * (double)Ww[64 + lane];
    double qs = (double)x0 * (double)Ww[128 + lane] + (double)x1 * (double)Ww[192 + lane];
    #pragma unroll
    for (int off = 32; off > 0; off >>= 1) {
        ps += __shfl_down(ps, off);
        qs += __shfl_down(qs, off);
    }
    if (lane == 0) { p[wid] = ps; q[wid] = qs; }
}

__global__ __launch_bounds__(256) void k_edge(
    const float* __restrict__ T, const double* __restrict__ p,
    const double* __restrict__ q, const float* __restrict__ bf,
    const float* __restrict__ bwp, const int* __restrict__ src,
    const int* __restrict__ tgt, float* __restrict__ out,
    double* __restrict__ den, int E)
{
    int e    = (blockIdx.x * 256 + threadIdx.x) >> 6;   // one wave per edge
    int lane = threadIdx.x & 63;
    if (e >= E) return;
    int s  = src[e];
    int tg = tgt[e];

    float2 U = ((const float2*)(T + (size_t)s  * 256))[lane];
    float2 V = ((const float2*)(T + (size_t)tg * 256 + 128))[lane];
    float2 b = ((const float2*)bf)[lane];

    double a  = p[s] + q[tg] + (double)bwp[0];
    float  af = (float)a;

    float y0 = fmaxf(U.x + V.x + b.x, 0.f);
    float y1 = fmaxf(U.y + V.y + b.y, 0.f);

    float* orow = out + (size_t)tg * 128 + lane * 2;
    atomicAdd(orow,     y0 * af);
    atomicAdd(orow + 1, y1 * af);
    if (lane == 0) atomicAdd(den + tg, a);
}

__global__ __launch_bounds__(256) void k_div(
    float* __restrict__ out, const double* __restrict__ den, int total)
{
    int i = blockIdx.x * 256 + threadIdx.x;
    if (i >= total) return;
    double d = den[i >> 7] + 1e-6;
    out[i] = (float)((double)out[i] / d);
}

extern "C" void kernel_launch(void* const* d_in, const int* in_sizes, int n_in,
                              void* d_out, int out_size, void* d_ws, size_t ws_size,
                              hipStream_t stream)
{
    const float* x   = (const float*)d_in[0];
    const float* Wf  = (const float*)d_in[1];
    const float* bf  = (const float*)d_in[2];
    const float* Ww  = (const float*)d_in[3];
    const float* bw  = (const float*)d_in[4];
    const int*   src = (const int*)d_in[5];
    const int*   tgt = (const int*)d_in[6];

    const int N = in_sizes[0] / 128;
    const int E = in_sizes[5];
    float* out = (float*)d_out;

    // workspace layout: T[N*256] f32 | p[N] f64 | q[N] f64 | den[N] f64
    char* w = (char*)d_ws;
    float*  T   = (float*)w;
    double* p   = (double*)(w + (size_t)N * 256 * sizeof(float));
    double* q   = p + N;
    double* den = q + N;

    hipMemsetAsync(out, 0, (size_t)N * 128 * sizeof(float), stream);
    hipMemsetAsync(den, 0, (size_t)N * sizeof(double), stream);

    dim3 g1((N + 63) / 64, 4);
    k_node_transform<<<g1, 256, 0, stream>>>(x, Wf, T, N);

    k_pq<<<(N * 64 + 255) / 256, 256, 0, stream>>>(x, Ww, p, q, N);

    long long ethreads = (long long)E * 64;
    k_edge<<<(int)((ethreads + 255) / 256), 256, 0, stream>>>(
        T, p, q, bf, bw, src, tgt, out, den, E);

    int total = N * 128;
    k_div<<<(total + 255) / 256, 256, 0, stream>>>(out, den, total);
}

// Round 2
// 395.783 us; speedup vs baseline: 2.2568x; 2.2568x over previous
//
#include <hip/hip_runtime.h>

// ---------------------------------------------------------------------------
// GAT edge-average layer, MI355X — CSR-aggregated version (no output atomics).
// Phase 1a: T[n][0:128]=x[n]@Wf1.T, T[n][128:256]=x[n]@Wf2.T (f32 tile GEMM)
// Phase 1b: p[n]=x[n].w1, q[n]=x[n].w2 (f64)
// Phase 2 : CSR build — histogram tgt, 2-level exclusive scan, scatter src
// Phase 3 : one wave per node: loop edges, acc += relu(U[s]+V[n]+bf)*a (f64),
//           asum += a (f64), single write out[n] = acc/(asum+eps)
// ---------------------------------------------------------------------------

__global__ __launch_bounds__(256) void k_node_transform(
    const float* __restrict__ x, const float* __restrict__ Wf,
    float* __restrict__ T, int N)
{
    __shared__ float xs[64][128];
    __shared__ float ws[64][128];
    const int t  = threadIdx.x;
    const int n0 = blockIdx.x * 64;
    const int c0 = blockIdx.y * 64;   // col tile: 0,64,128,192

    #pragma unroll
    for (int i = 0; i < 8; ++i) {
        int idx = t + i * 256;          // 0..2047 float4 slots
        int row = idx >> 5;
        int c4  = idx & 31;
        int n = n0 + row;
        float4 v = make_float4(0.f, 0.f, 0.f, 0.f);
        if (n < N) v = *(const float4*)(x + (size_t)n * 128 + c4 * 4);
        *(float4*)(&xs[row][(c4 ^ (row & 7)) * 4]) = v;
    }
    #pragma unroll
    for (int i = 0; i < 8; ++i) {
        int idx = t + i * 256;
        int row = idx >> 5;             // col within tile
        int c4  = idx & 31;
        int c = c0 + row;
        const float* wsrc = (c < 128) ? (Wf + (size_t)c * 256 + c4 * 4)
                                      : (Wf + (size_t)(c - 128) * 256 + 128 + c4 * 4);
        *(float4*)(&ws[row][(c4 ^ (row & 7)) * 4]) = *(const float4*)wsrc;
    }
    __syncthreads();

    const int tx = t & 15, ty = t >> 4;
    float acc[4][4] = {};
    #pragma unroll 8
    for (int k4 = 0; k4 < 32; ++k4) {
        float4 xv[4], wv[4];
        #pragma unroll
        for (int i = 0; i < 4; ++i) {
            int r = ty * 4 + i;
            xv[i] = *(const float4*)(&xs[r][(k4 ^ (r & 7)) * 4]);
        }
        #pragma unroll
        for (int j = 0; j < 4; ++j) {
            int r = tx + 16 * j;
            wv[j] = *(const float4*)(&ws[r][(k4 ^ (r & 7)) * 4]);
        }
        #pragma unroll
        for (int i = 0; i < 4; ++i)
            #pragma unroll
            for (int j = 0; j < 4; ++j)
                acc[i][j] += xv[i].x * wv[j].x + xv[i].y * wv[j].y
                           + xv[i].z * wv[j].z + xv[i].w * wv[j].w;
    }

    #pragma unroll
    for (int i = 0; i < 4; ++i) {
        int n = n0 + ty * 4 + i;
        if (n < N) {
            float* Trow = T + (size_t)n * 256 + c0;
            #pragma unroll
            for (int j = 0; j < 4; ++j)
                Trow[tx + 16 * j] = acc[i][j];
        }
    }
}

__global__ __launch_bounds__(256) void k_pq(
    const float* __restrict__ x, const float* __restrict__ Ww,
    double* __restrict__ p, double* __restrict__ q, int N)
{
    int wid  = (blockIdx.x * 256 + threadIdx.x) >> 6;   // one wave per node
    int lane = threadIdx.x & 63;
    if (wid >= N) return;
    const float* xr = x + (size_t)wid * 128;
    float x0 = xr[lane], x1 = xr[64 + lane];
    double ps = (double)x0 * (double)Ww[lane]       + (double)x1 * (double)Ww[64 + lane];
    double qs = (double)x0 * (double)Ww[128 + lane] + (double)x1 * (double)Ww[192 + lane];
    #pragma unroll
    for (int off = 32; off > 0; off >>= 1) {
        ps += __shfl_down(ps, off);
        qs += __shfl_down(qs, off);
    }
    if (lane == 0) { p[wid] = ps; q[wid] = qs; }
}

// ---------------- CSR build ----------------

__global__ __launch_bounds__(256) void k_hist(
    const int* __restrict__ tgt, int* __restrict__ counts, int E)
{
    int e = blockIdx.x * 256 + threadIdx.x;
    if (e < E) atomicAdd(&counts[tgt[e]], 1);
}

__global__ __launch_bounds__(256) void k_scan1(
    const int* __restrict__ counts, int* __restrict__ incl,
    int* __restrict__ partials, int N)
{
    __shared__ int sh[256];
    int t = threadIdx.x;
    int i = blockIdx.x * 256 + t;
    int v = (i < N) ? counts[i] : 0;
    sh[t] = v;
    __syncthreads();
    #pragma unroll
    for (int off = 1; off < 256; off <<= 1) {
        int add = (t >= off) ? sh[t - off] : 0;
        __syncthreads();
        sh[t] += add;
        __syncthreads();
    }
    if (i < N) incl[i] = sh[t];
    if (t == 255) partials[blockIdx.x] = sh[255];
}

__global__ __launch_bounds__(256) void k_scan2(int* __restrict__ partials, int nb)
{
    __shared__ int sh[256];
    int t = threadIdx.x;
    int v = (t < nb) ? partials[t] : 0;
    sh[t] = v;
    __syncthreads();
    #pragma unroll
    for (int off = 1; off < 256; off <<= 1) {
        int add = (t >= off) ? sh[t - off] : 0;
        __syncthreads();
        sh[t] += add;
        __syncthreads();
    }
    if (t < nb) partials[t] = sh[t] - v;   // exclusive
}

__global__ __launch_bounds__(256) void k_scan3(
    const int* __restrict__ counts, const int* __restrict__ incl,
    const int* __restrict__ partials, int* __restrict__ offsets,
    int* __restrict__ cursor, int N)
{
    int i = blockIdx.x * 256 + threadIdx.x;
    if (i >= N) return;
    int off = incl[i] - counts[i] + partials[i >> 8];
    offsets[i] = off;
    cursor[i]  = off;
}

__global__ __launch_bounds__(256) void k_scatter(
    const int* __restrict__ src, const int* __restrict__ tgt,
    int* __restrict__ cursor, int* __restrict__ srcs, int E)
{
    int e = blockIdx.x * 256 + threadIdx.x;
    if (e >= E) return;
    int pos = atomicAdd(&cursor[tgt[e]], 1);
    srcs[pos] = src[e];
}

// ---------------- node aggregation (one wave per target node) ----------------

__global__ __launch_bounds__(256) void k_node(
    const float* __restrict__ T, const double* __restrict__ p,
    const double* __restrict__ q, const float* __restrict__ bf,
    const float* __restrict__ bwp, const int* __restrict__ offsets,
    const int* __restrict__ counts, const int* __restrict__ srcs,
    float* __restrict__ out, int N)
{
    int n    = (blockIdx.x * 256 + threadIdx.x) >> 6;
    int lane = threadIdx.x & 63;
    if (n >= N) return;

    float2 b  = ((const float2*)bf)[lane];
    float2 Vn = ((const float2*)(T + (size_t)n * 256 + 128))[lane];
    Vn.x += b.x; Vn.y += b.y;
    double qn = q[n] + (double)bwp[0];

    int beg = offsets[n];
    int cnt = counts[n];

    double ax = 0.0, ay = 0.0, asum = 0.0;
    for (int i = 0; i < cnt; ++i) {
        int s = srcs[beg + i];
        float2 U = ((const float2*)(T + (size_t)s * 256))[lane];
        double a = p[s] + qn;
        float af = (float)a;
        ax += (double)(fmaxf(U.x + Vn.x, 0.f) * af);
        ay += (double)(fmaxf(U.y + Vn.y, 0.f) * af);
        asum += a;
    }
    double inv = 1.0 / (asum + 1e-6);
    float2 o;
    o.x = (float)(ax * inv);
    o.y = (float)(ay * inv);
    ((float2*)(out + (size_t)n * 128))[lane] = o;
}

extern "C" void kernel_launch(void* const* d_in, const int* in_sizes, int n_in,
                              void* d_out, int out_size, void* d_ws, size_t ws_size,
                              hipStream_t stream)
{
    const float* x   = (const float*)d_in[0];
    const float* Wf  = (const float*)d_in[1];
    const float* bf  = (const float*)d_in[2];
    const float* Ww  = (const float*)d_in[3];
    const float* bw  = (const float*)d_in[4];
    const int*   src = (const int*)d_in[5];
    const int*   tgt = (const int*)d_in[6];

    const int N = in_sizes[0] / 128;
    const int E = in_sizes[5];
    float* out = (float*)d_out;

    // workspace layout
    char* w = (char*)d_ws;
    float*  T        = (float*)w;                 w += (size_t)N * 256 * sizeof(float);
    double* p        = (double*)w;                w += (size_t)N * sizeof(double);
    double* q        = (double*)w;                w += (size_t)N * sizeof(double);
    int*    counts   = (int*)w;                   w += (size_t)N * sizeof(int);
    int*    incl     = (int*)w;                   w += (size_t)N * sizeof(int);
    int*    offsets  = (int*)w;                   w += (size_t)N * sizeof(int);
    int*    cursor   = (int*)w;                   w += (size_t)N * sizeof(int);
    int*    partials = (int*)w;                   w += 4096;
    int*    srcs     = (int*)w;                   // E ints

    hipMemsetAsync(counts, 0, (size_t)N * sizeof(int), stream);

    dim3 g1((N + 63) / 64, 4);
    k_node_transform<<<g1, 256, 0, stream>>>(x, Wf, T, N);
    k_pq<<<(N * 64 + 255) / 256, 256, 0, stream>>>(x, Ww, p, q, N);

    int ebk = (E + 255) / 256;
    int nbk = (N + 255) / 256;
    k_hist<<<ebk, 256, 0, stream>>>(tgt, counts, E);
    k_scan1<<<nbk, 256, 0, stream>>>(counts, incl, partials, N);
    k_scan2<<<1, 256, 0, stream>>>(partials, nbk);
    k_scan3<<<nbk, 256, 0, stream>>>(counts, incl, partials, offsets, cursor, N);
    k_scatter<<<ebk, 256, 0, stream>>>(src, tgt, cursor, srcs, E);

    long long nthreads = (long long)N * 64;
    k_node<<<(int)((nthreads + 255) / 256), 256, 0, stream>>>(
        T, p, q, bf, bw, offsets, counts, srcs, out, N);
}

// Round 3
// 322.843 us; speedup vs baseline: 2.7667x; 1.2259x over previous
//
#include <hip/hip_runtime.h>

// ---------------------------------------------------------------------------
// GAT edge-average layer, MI355X — CSR aggregation, split U/V tables, fused pq.
// Phase 1 : U[n]=x[n]@Wf1.T ; Vb[n]=x[n]@Wf2.T+bf ; p[n]=x.w1 ; q[n]=x.w2+bw
// Phase 2 : CSR build — histogram tgt, 2-level exclusive scan, scatter src
// Phase 3 : 32 lanes per node, 4-edge unrolled gather loop, f64 accum,
//           single float4 write per lane. No atomics on output.
// ---------------------------------------------------------------------------

__global__ __launch_bounds__(256) void k_node_transform(
    const float* __restrict__ x, const float* __restrict__ Wf,
    const float* __restrict__ bf, const float* __restrict__ Ww,
    const float* __restrict__ bw,
    float* __restrict__ U, float* __restrict__ Vb,
    double* __restrict__ p, double* __restrict__ q, int N)
{
    __shared__ float xs[64][128];
    __shared__ float ws[64][128];
    const int t  = threadIdx.x;
    const int n0 = blockIdx.x * 64;
    const int c0 = blockIdx.y * 64;   // col tile: 0,64,128,192

    #pragma unroll
    for (int i = 0; i < 8; ++i) {
        int idx = t + i * 256;          // 0..2047 float4 slots
        int row = idx >> 5;
        int c4  = idx & 31;
        int n = n0 + row;
        float4 v = make_float4(0.f, 0.f, 0.f, 0.f);
        if (n < N) v = *(const float4*)(x + (size_t)n * 128 + c4 * 4);
        *(float4*)(&xs[row][(c4 ^ (row & 7)) * 4]) = v;
    }
    #pragma unroll
    for (int i = 0; i < 8; ++i) {
        int idx = t + i * 256;
        int row = idx >> 5;             // col within tile
        int c4  = idx & 31;
        int c = c0 + row;
        const float* wsrc = (c < 128) ? (Wf + (size_t)c * 256 + c4 * 4)
                                      : (Wf + (size_t)(c - 128) * 256 + 128 + c4 * 4);
        *(float4*)(&ws[row][(c4 ^ (row & 7)) * 4]) = *(const float4*)wsrc;
    }
    __syncthreads();

    // ---- fused p/q (f64) in the c0==0 blocks: 4 threads per node ----
    if (blockIdx.y == 0) {
        const int r  = t >> 2;          // node row 0..63
        const int ch = (t & 3) * 32;    // k-chunk
        double ps = 0.0, qs = 0.0;
        #pragma unroll 8
        for (int k = ch; k < ch + 32; ++k) {
            float xv = xs[r][(((k >> 2) ^ (r & 7)) << 2) | (k & 3)];
            ps += (double)xv * (double)Ww[k];
            qs += (double)xv * (double)Ww[128 + k];
        }
        ps += __shfl_xor(ps, 1); ps += __shfl_xor(ps, 2);
        qs += __shfl_xor(qs, 1); qs += __shfl_xor(qs, 2);
        if ((t & 3) == 0 && (n0 + r) < N) {
            p[n0 + r] = ps;
            q[n0 + r] = qs + (double)bw[0];
        }
    }

    const int tx = t & 15, ty = t >> 4;
    float acc[4][4] = {};
    #pragma unroll 8
    for (int k4 = 0; k4 < 32; ++k4) {
        float4 xv[4], wv[4];
        #pragma unroll
        for (int i = 0; i < 4; ++i) {
            int r = ty * 4 + i;
            xv[i] = *(const float4*)(&xs[r][(k4 ^ (r & 7)) * 4]);
        }
        #pragma unroll
        for (int j = 0; j < 4; ++j) {
            int r = tx + 16 * j;
            wv[j] = *(const float4*)(&ws[r][(k4 ^ (r & 7)) * 4]);
        }
        #pragma unroll
        for (int i = 0; i < 4; ++i)
            #pragma unroll
            for (int j = 0; j < 4; ++j)
                acc[i][j] += xv[i].x * wv[j].x + xv[i].y * wv[j].y
                           + xv[i].z * wv[j].z + xv[i].w * wv[j].w;
    }

    const bool isV = (c0 >= 128);
    #pragma unroll
    for (int i = 0; i < 4; ++i) {
        int n = n0 + ty * 4 + i;
        if (n < N) {
            if (!isV) {
                float* dst = U + (size_t)n * 128 + c0;
                #pragma unroll
                for (int j = 0; j < 4; ++j)
                    dst[tx + 16 * j] = acc[i][j];
            } else {
                float* dst = Vb + (size_t)n * 128 + (c0 - 128);
                #pragma unroll
                for (int j = 0; j < 4; ++j)
                    dst[tx + 16 * j] = acc[i][j] + bf[(c0 - 128) + tx + 16 * j];
            }
        }
    }
}

// ---------------- CSR build ----------------

__global__ __launch_bounds__(256) void k_hist(
    const int* __restrict__ tgt, int* __restrict__ counts, int E)
{
    int e = blockIdx.x * 256 + threadIdx.x;
    if (e < E) atomicAdd(&counts[tgt[e]], 1);
}

__global__ __launch_bounds__(256) void k_scan1(
    const int* __restrict__ counts, int* __restrict__ incl,
    int* __restrict__ partials, int N)
{
    __shared__ int sh[256];
    int t = threadIdx.x;
    int i = blockIdx.x * 256 + t;
    int v = (i < N) ? counts[i] : 0;
    sh[t] = v;
    __syncthreads();
    #pragma unroll
    for (int off = 1; off < 256; off <<= 1) {
        int add = (t >= off) ? sh[t - off] : 0;
        __syncthreads();
        sh[t] += add;
        __syncthreads();
    }
    if (i < N) incl[i] = sh[t];
    if (t == 255) partials[blockIdx.x] = sh[255];
}

__global__ __launch_bounds__(256) void k_scan2(int* __restrict__ partials, int nb)
{
    __shared__ int sh[256];
    int t = threadIdx.x;
    int v = (t < nb) ? partials[t] : 0;
    sh[t] = v;
    __syncthreads();
    #pragma unroll
    for (int off = 1; off < 256; off <<= 1) {
        int add = (t >= off) ? sh[t - off] : 0;
        __syncthreads();
        sh[t] += add;
        __syncthreads();
    }
    if (t < nb) partials[t] = sh[t] - v;   // exclusive
}

__global__ __launch_bounds__(256) void k_scan3(
    const int* __restrict__ counts, const int* __restrict__ incl,
    const int* __restrict__ partials, int* __restrict__ offsets,
    int* __restrict__ cursor, int N)
{
    int i = blockIdx.x * 256 + threadIdx.x;
    if (i >= N) return;
    int off = incl[i] - counts[i] + partials[i >> 8];
    offsets[i] = off;
    cursor[i]  = off;
}

__global__ __launch_bounds__(256) void k_scatter(
    const int* __restrict__ src, const int* __restrict__ tgt,
    int* __restrict__ cursor, int* __restrict__ srcs, int E)
{
    int e = blockIdx.x * 256 + threadIdx.x;
    if (e >= E) return;
    int pos = atomicAdd(&cursor[tgt[e]], 1);
    srcs[pos] = src[e];
}

// ------------- node aggregation: 32 lanes/node, 4-edge pipeline -------------

__global__ __launch_bounds__(256) void k_node(
    const float* __restrict__ U, const float* __restrict__ Vb,
    const double* __restrict__ p, const double* __restrict__ q,
    const int* __restrict__ offsets, const int* __restrict__ counts,
    const int* __restrict__ srcs, float* __restrict__ out, int N)
{
    int idx  = blockIdx.x * 256 + threadIdx.x;
    int n    = idx >> 5;                 // 32 lanes per node
    int lane = threadIdx.x & 31;
    if (n >= N) return;

    float4 Vn = ((const float4*)(Vb + (size_t)n * 128))[lane];
    double qn = q[n];                    // includes bw
    int beg = offsets[n];
    int cnt = counts[n];

    double ax = 0.0, ay = 0.0, az = 0.0, aw = 0.0, asum = 0.0;

    int i = 0;
    for (; i + 4 <= cnt; i += 4) {
        int s0 = srcs[beg + i + 0];
        int s1 = srcs[beg + i + 1];
        int s2 = srcs[beg + i + 2];
        int s3 = srcs[beg + i + 3];
        float4 U0 = ((const float4*)(U + (size_t)s0 * 128))[lane];
        float4 U1 = ((const float4*)(U + (size_t)s1 * 128))[lane];
        float4 U2 = ((const float4*)(U + (size_t)s2 * 128))[lane];
        float4 U3 = ((const float4*)(U + (size_t)s3 * 128))[lane];
        double a0 = p[s0] + qn, a1 = p[s1] + qn, a2 = p[s2] + qn, a3 = p[s3] + qn;
        float f0 = (float)a0, f1 = (float)a1, f2 = (float)a2, f3 = (float)a3;

        ax += (double)(fmaxf(U0.x + Vn.x, 0.f) * f0);
        ay += (double)(fmaxf(U0.y + Vn.y, 0.f) * f0);
        az += (double)(fmaxf(U0.z + Vn.z, 0.f) * f0);
        aw += (double)(fmaxf(U0.w + Vn.w, 0.f) * f0);
        asum += a0;
        ax += (double)(fmaxf(U1.x + Vn.x, 0.f) * f1);
        ay += (double)(fmaxf(U1.y + Vn.y, 0.f) * f1);
        az += (double)(fmaxf(U1.z + Vn.z, 0.f) * f1);
        aw += (double)(fmaxf(U1.w + Vn.w, 0.f) * f1);
        asum += a1;
        ax += (double)(fmaxf(U2.x + Vn.x, 0.f) * f2);
        ay += (double)(fmaxf(U2.y + Vn.y, 0.f) * f2);
        az += (double)(fmaxf(U2.z + Vn.z, 0.f) * f2);
        aw += (double)(fmaxf(U2.w + Vn.w, 0.f) * f2);
        asum += a2;
        ax += (double)(fmaxf(U3.x + Vn.x, 0.f) * f3);
        ay += (double)(fmaxf(U3.y + Vn.y, 0.f) * f3);
        az += (double)(fmaxf(U3.z + Vn.z, 0.f) * f3);
        aw += (double)(fmaxf(U3.w + Vn.w, 0.f) * f3);
        asum += a3;
    }
    for (; i < cnt; ++i) {
        int s = srcs[beg + i];
        float4 Ue = ((const float4*)(U + (size_t)s * 128))[lane];
        double a = p[s] + qn;
        float af = (float)a;
        ax += (double)(fmaxf(Ue.x + Vn.x, 0.f) * af);
        ay += (double)(fmaxf(Ue.y + Vn.y, 0.f) * af);
        az += (double)(fmaxf(Ue.z + Vn.z, 0.f) * af);
        aw += (double)(fmaxf(Ue.w + Vn.w, 0.f) * af);
        asum += a;
    }

    double inv = 1.0 / (asum + 1e-6);
    float4 o;
    o.x = (float)(ax * inv);
    o.y = (float)(ay * inv);
    o.z = (float)(az * inv);
    o.w = (float)(aw * inv);
    ((float4*)(out + (size_t)n * 128))[lane] = o;
}

extern "C" void kernel_launch(void* const* d_in, const int* in_sizes, int n_in,
                              void* d_out, int out_size, void* d_ws, size_t ws_size,
                              hipStream_t stream)
{
    const float* x   = (const float*)d_in[0];
    const float* Wf  = (const float*)d_in[1];
    const float* bf  = (const float*)d_in[2];
    const float* Ww  = (const float*)d_in[3];
    const float* bw  = (const float*)d_in[4];
    const int*   src = (const int*)d_in[5];
    const int*   tgt = (const int*)d_in[6];

    const int N = in_sizes[0] / 128;
    const int E = in_sizes[5];
    float* out = (float*)d_out;

    // workspace layout
    char* w = (char*)d_ws;
    float*  U        = (float*)w;                 w += (size_t)N * 128 * sizeof(float);
    float*  Vb       = (float*)w;                 w += (size_t)N * 128 * sizeof(float);
    double* p        = (double*)w;                w += (size_t)N * sizeof(double);
    double* q        = (double*)w;                w += (size_t)N * sizeof(double);
    int*    counts   = (int*)w;                   w += (size_t)N * sizeof(int);
    int*    incl     = (int*)w;                   w += (size_t)N * sizeof(int);
    int*    offsets  = (int*)w;                   w += (size_t)N * sizeof(int);
    int*    cursor   = (int*)w;                   w += (size_t)N * sizeof(int);
    int*    partials = (int*)w;                   w += 4096;
    int*    srcs     = (int*)w;                   // E ints

    hipMemsetAsync(counts, 0, (size_t)N * sizeof(int), stream);

    dim3 g1((N + 63) / 64, 4);
    k_node_transform<<<g1, 256, 0, stream>>>(x, Wf, bf, Ww, bw, U, Vb, p, q, N);

    int ebk = (E + 255) / 256;
    int nbk = (N + 255) / 256;
    k_hist<<<ebk, 256, 0, stream>>>(tgt, counts, E);
    k_scan1<<<nbk, 256, 0, stream>>>(counts, incl, partials, N);
    k_scan2<<<1, 256, 0, stream>>>(partials, nbk);
    k_scan3<<<nbk, 256, 0, stream>>>(counts, incl, partials, offsets, cursor, N);
    k_scatter<<<ebk, 256, 0, stream>>>(src, tgt, cursor, srcs, E);

    long long nthreads = (long long)N * 32;
    k_node<<<(int)((nthreads + 255) / 256), 256, 0, stream>>>(
        U, Vb, p, q, offsets, counts, srcs, out, N);
}

// Round 4
// 309.258 us; speedup vs baseline: 2.8882x; 1.0439x over previous
//
#include <hip/hip_runtime.h>

// ---------------------------------------------------------------------------
// GAT edge-average layer, MI355X.
// Phase 0 : k_wconv — Wf (f32) -> W' split-bf16 tables wh/wl [256][128]
// Phase 1 : k_transform — MFMA bf16x3: U[n]=x@Wf1.T, Vb[n]=x@Wf2.T+bf,
//           fused p[n]=x.w1, q[n]=x.w2+bw (f64). No LDS.
// Phase 2 : CSR build — histogram tgt, 2-level exclusive scan, scatter src
// Phase 3 : k_node — 32 lanes/node, 4-edge unrolled gather, f64 accum,
//           single float4 write per lane. No atomics on output.
// ---------------------------------------------------------------------------

typedef short bf16x8 __attribute__((ext_vector_type(8)));
typedef float f32x4  __attribute__((ext_vector_type(4)));

__device__ inline short f32_to_bf16_rne(float f) {
    unsigned u = __float_as_uint(f);
    unsigned r = u + 0x7fffu + ((u >> 16) & 1u);
    return (short)(r >> 16);
}
__device__ inline float bf16s_to_f32(short s) {
    return __uint_as_float(((unsigned)(unsigned short)s) << 16);
}

// W'[c][k]: c<128 -> Wf[c][k] ; c>=128 -> Wf[c-128][128+k]
__global__ __launch_bounds__(256) void k_wconv(
    const float* __restrict__ Wf, short* __restrict__ wh, short* __restrict__ wl)
{
    int i = blockIdx.x * 256 + threadIdx.x;       // 0..32767
    if (i >= 256 * 128) return;
    int c = i >> 7, k = i & 127;
    float v = (c < 128) ? Wf[c * 256 + k] : Wf[(c - 128) * 256 + 128 + k];
    short h = f32_to_bf16_rne(v);
    wh[i] = h;
    wl[i] = f32_to_bf16_rne(v - bf16s_to_f32(h));
}

__global__ __launch_bounds__(256) void k_transform(
    const float* __restrict__ x, const short* __restrict__ wh,
    const short* __restrict__ wl, const float* __restrict__ bf,
    const float* __restrict__ Ww, const float* __restrict__ bw,
    float* __restrict__ U, float* __restrict__ Vb,
    double* __restrict__ p, double* __restrict__ q, int N)
{
    const int wv   = threadIdx.x >> 6;            // wave 0..3
    const int lane = threadIdx.x & 63;
    const int r16  = lane & 15;                   // A-row / C-col within tile
    const int kb   = lane >> 4;                   // k-block (8 elems)
    const int n0   = blockIdx.x * 64 + wv * 16;   // first node of this wave
    const int nrow = n0 + r16;
    const int ncl  = (nrow < N) ? nrow : (N - 1);

    // ---- load this lane's A chunks: 4 k-tiles x 8 f32 at k = kt*32 + kb*8 ----
    float a_f[4][8];
    const float* xr = x + (size_t)ncl * 128 + kb * 8;
    #pragma unroll
    for (int kt = 0; kt < 4; ++kt) {
        f32x4 v0 = *(const f32x4*)(xr + kt * 32);
        f32x4 v1 = *(const f32x4*)(xr + kt * 32 + 4);
        a_f[kt][0] = v0.x; a_f[kt][1] = v0.y; a_f[kt][2] = v0.z; a_f[kt][3] = v0.w;
        a_f[kt][4] = v1.x; a_f[kt][5] = v1.y; a_f[kt][6] = v1.z; a_f[kt][7] = v1.w;
    }

    // ---- fused p/q (f64): lanes {r16, r16+16, r16+32, r16+48} share a row ----
    double ps = 0.0, qs = 0.0;
    #pragma unroll
    for (int kt = 0; kt < 4; ++kt)
        #pragma unroll
        for (int j = 0; j < 8; ++j) {
            int k = kt * 32 + kb * 8 + j;
            ps += (double)a_f[kt][j] * (double)Ww[k];
            qs += (double)a_f[kt][j] * (double)Ww[128 + k];
        }
    ps += __shfl_xor(ps, 16); ps += __shfl_xor(ps, 32);
    qs += __shfl_xor(qs, 16); qs += __shfl_xor(qs, 32);
    if (lane < 16 && nrow < N) {
        p[nrow] = ps;
        q[nrow] = qs + (double)bw[0];
    }

    // ---- convert A to split bf16 fragments ----
    bf16x8 ah[4], al[4];
    #pragma unroll
    for (int kt = 0; kt < 4; ++kt) {
        bf16x8 h, l;
        #pragma unroll
        for (int j = 0; j < 8; ++j) {
            float f = a_f[kt][j];
            short hs = f32_to_bf16_rne(f);
            h[j] = hs;
            l[j] = f32_to_bf16_rne(f - bf16s_to_f32(hs));
        }
        ah[kt] = h; al[kt] = l;
    }

    // ---- 16 col-tiles of 16: bf16x3 MFMA, direct global B-frags ----
    #pragma unroll 2
    for (int ct = 0; ct < 16; ++ct) {
        int c = ct * 16 + r16;                    // output col 0..255
        const short* whr = wh + (size_t)c * 128 + kb * 8;
        const short* wlr = wl + (size_t)c * 128 + kb * 8;
        f32x4 acc = {0.f, 0.f, 0.f, 0.f};
        #pragma unroll
        for (int kt = 0; kt < 4; ++kt) {
            bf16x8 bh = *(const bf16x8*)(whr + kt * 32);
            bf16x8 bl = *(const bf16x8*)(wlr + kt * 32);
            acc = __builtin_amdgcn_mfma_f32_16x16x32_bf16(ah[kt], bh, acc, 0, 0, 0);
            acc = __builtin_amdgcn_mfma_f32_16x16x32_bf16(ah[kt], bl, acc, 0, 0, 0);
            acc = __builtin_amdgcn_mfma_f32_16x16x32_bf16(al[kt], bh, acc, 0, 0, 0);
        }
        // C/D layout: col = lane&15 (= c), row = kb*4 + i
        if (ct < 8) {
            #pragma unroll
            for (int i = 0; i < 4; ++i) {
                int nst = n0 + kb * 4 + i;
                if (nst < N) U[(size_t)nst * 128 + c] = acc[i];
            }
        } else {
            float bias = bf[c - 128];
            #pragma unroll
            for (int i = 0; i < 4; ++i) {
                int nst = n0 + kb * 4 + i;
                if (nst < N) Vb[(size_t)nst * 128 + (c - 128)] = acc[i] + bias;
            }
        }
    }
}

// ---------------- CSR build ----------------

__global__ __launch_bounds__(256) void k_hist(
    const int* __restrict__ tgt, int* __restrict__ counts, int E)
{
    int e = blockIdx.x * 256 + threadIdx.x;
    if (e < E) atomicAdd(&counts[tgt[e]], 1);
}

__global__ __launch_bounds__(256) void k_scan1(
    const int* __restrict__ counts, int* __restrict__ incl,
    int* __restrict__ partials, int N)
{
    __shared__ int sh[256];
    int t = threadIdx.x;
    int i = blockIdx.x * 256 + t;
    int v = (i < N) ? counts[i] : 0;
    sh[t] = v;
    __syncthreads();
    #pragma unroll
    for (int off = 1; off < 256; off <<= 1) {
        int add = (t >= off) ? sh[t - off] : 0;
        __syncthreads();
        sh[t] += add;
        __syncthreads();
    }
    if (i < N) incl[i] = sh[t];
    if (t == 255) partials[blockIdx.x] = sh[255];
}

__global__ __launch_bounds__(256) void k_scan2(int* __restrict__ partials, int nb)
{
    __shared__ int sh[256];
    int t = threadIdx.x;
    int v = (t < nb) ? partials[t] : 0;
    sh[t] = v;
    __syncthreads();
    #pragma unroll
    for (int off = 1; off < 256; off <<= 1) {
        int add = (t >= off) ? sh[t - off] : 0;
        __syncthreads();
        sh[t] += add;
        __syncthreads();
    }
    if (t < nb) partials[t] = sh[t] - v;   // exclusive
}

__global__ __launch_bounds__(256) void k_scan3(
    const int* __restrict__ counts, const int* __restrict__ incl,
    const int* __restrict__ partials, int* __restrict__ offsets,
    int* __restrict__ cursor, int N)
{
    int i = blockIdx.x * 256 + threadIdx.x;
    if (i >= N) return;
    int off = incl[i] - counts[i] + partials[i >> 8];
    offsets[i] = off;
    cursor[i]  = off;
}

__global__ __launch_bounds__(256) void k_scatter(
    const int* __restrict__ src, const int* __restrict__ tgt,
    int* __restrict__ cursor, int* __restrict__ srcs, int E)
{
    int e = blockIdx.x * 256 + threadIdx.x;
    if (e >= E) return;
    int pos = atomicAdd(&cursor[tgt[e]], 1);
    srcs[pos] = src[e];
}

// ------------- node aggregation: 32 lanes/node, 4-edge pipeline -------------

__global__ __launch_bounds__(256) void k_node(
    const float* __restrict__ U, const float* __restrict__ Vb,
    const double* __restrict__ p, const double* __restrict__ q,
    const int* __restrict__ offsets, const int* __restrict__ counts,
    const int* __restrict__ srcs, float* __restrict__ out, int N)
{
    int idx  = blockIdx.x * 256 + threadIdx.x;
    int n    = idx >> 5;                 // 32 lanes per node
    int lane = threadIdx.x & 31;
    if (n >= N) return;

    float4 Vn = ((const float4*)(Vb + (size_t)n * 128))[lane];
    double qn = q[n];                    // includes bw
    int beg = offsets[n];
    int cnt = counts[n];

    double ax = 0.0, ay = 0.0, az = 0.0, aw = 0.0, asum = 0.0;

    int i = 0;
    for (; i + 4 <= cnt; i += 4) {
        int s0 = srcs[beg + i + 0];
        int s1 = srcs[beg + i + 1];
        int s2 = srcs[beg + i + 2];
        int s3 = srcs[beg + i + 3];
        float4 U0 = ((const float4*)(U + (size_t)s0 * 128))[lane];
        float4 U1 = ((const float4*)(U + (size_t)s1 * 128))[lane];
        float4 U2 = ((const float4*)(U + (size_t)s2 * 128))[lane];
        float4 U3 = ((const float4*)(U + (size_t)s3 * 128))[lane];
        double a0 = p[s0] + qn, a1 = p[s1] + qn, a2 = p[s2] + qn, a3 = p[s3] + qn;
        float f0 = (float)a0, f1 = (float)a1, f2 = (float)a2, f3 = (float)a3;

        ax += (double)(fmaxf(U0.x + Vn.x, 0.f) * f0);
        ay += (double)(fmaxf(U0.y + Vn.y, 0.f) * f0);
        az += (double)(fmaxf(U0.z + Vn.z, 0.f) * f0);
        aw += (double)(fmaxf(U0.w + Vn.w, 0.f) * f0);
        asum += a0;
        ax += (double)(fmaxf(U1.x + Vn.x, 0.f) * f1);
        ay += (double)(fmaxf(U1.y + Vn.y, 0.f) * f1);
        az += (double)(fmaxf(U1.z + Vn.z, 0.f) * f1);
        aw += (double)(fmaxf(U1.w + Vn.w, 0.f) * f1);
        asum += a1;
        ax += (double)(fmaxf(U2.x + Vn.x, 0.f) * f2);
        ay += (double)(fmaxf(U2.y + Vn.y, 0.f) * f2);
        az += (double)(fmaxf(U2.z + Vn.z, 0.f) * f2);
        aw += (double)(fmaxf(U2.w + Vn.w, 0.f) * f2);
        asum += a2;
        ax += (double)(fmaxf(U3.x + Vn.x, 0.f) * f3);
        ay += (double)(fmaxf(U3.y + Vn.y, 0.f) * f3);
        az += (double)(fmaxf(U3.z + Vn.z, 0.f) * f3);
        aw += (double)(fmaxf(U3.w + Vn.w, 0.f) * f3);
        asum += a3;
    }
    for (; i < cnt; ++i) {
        int s = srcs[beg + i];
        float4 Ue = ((const float4*)(U + (size_t)s * 128))[lane];
        double a = p[s] + qn;
        float af = (float)a;
        ax += (double)(fmaxf(Ue.x + Vn.x, 0.f) * af);
        ay += (double)(fmaxf(Ue.y + Vn.y, 0.f) * af);
        az += (double)(fmaxf(Ue.z + Vn.z, 0.f) * af);
        aw += (double)(fmaxf(Ue.w + Vn.w, 0.f) * af);
        asum += a;
    }

    double inv = 1.0 / (asum + 1e-6);
    float4 o;
    o.x = (float)(ax * inv);
    o.y = (float)(ay * inv);
    o.z = (float)(az * inv);
    o.w = (float)(aw * inv);
    ((float4*)(out + (size_t)n * 128))[lane] = o;
}

extern "C" void kernel_launch(void* const* d_in, const int* in_sizes, int n_in,
                              void* d_out, int out_size, void* d_ws, size_t ws_size,
                              hipStream_t stream)
{
    const float* x   = (const float*)d_in[0];
    const float* Wf  = (const float*)d_in[1];
    const float* bf  = (const float*)d_in[2];
    const float* Ww  = (const float*)d_in[3];
    const float* bw  = (const float*)d_in[4];
    const int*   src = (const int*)d_in[5];
    const int*   tgt = (const int*)d_in[6];

    const int N = in_sizes[0] / 128;
    const int E = in_sizes[5];
    float* out = (float*)d_out;

    // workspace layout
    char* w = (char*)d_ws;
    float*  U        = (float*)w;                 w += (size_t)N * 128 * sizeof(float);
    float*  Vb       = (float*)w;                 w += (size_t)N * 128 * sizeof(float);
    double* p        = (double*)w;                w += (size_t)N * sizeof(double);
    double* q        = (double*)w;                w += (size_t)N * sizeof(double);
    int*    counts   = (int*)w;                   w += (size_t)N * sizeof(int);
    int*    incl     = (int*)w;                   w += (size_t)N * sizeof(int);
    int*    offsets  = (int*)w;                   w += (size_t)N * sizeof(int);
    int*    cursor   = (int*)w;                   w += (size_t)N * sizeof(int);
    int*    partials = (int*)w;                   w += 4096;
    int*    srcs     = (int*)w;                   w += (size_t)E * sizeof(int);
    short*  wh       = (short*)w;                 w += 256 * 128 * sizeof(short);
    short*  wl       = (short*)w;

    hipMemsetAsync(counts, 0, (size_t)N * sizeof(int), stream);

    k_wconv<<<128, 256, 0, stream>>>(Wf, wh, wl);
    k_transform<<<(N + 63) / 64, 256, 0, stream>>>(
        x, wh, wl, bf, Ww, bw, U, Vb, p, q, N);

    int ebk = (E + 255) / 256;
    int nbk = (N + 255) / 256;
    k_hist<<<ebk, 256, 0, stream>>>(tgt, counts, E);
    k_scan1<<<nbk, 256, 0, stream>>>(counts, incl, partials, N);
    k_scan2<<<1, 256, 0, stream>>>(partials, nbk);
    k_scan3<<<nbk, 256, 0, stream>>>(counts, incl, partials, offsets, cursor, N);
    k_scatter<<<ebk, 256, 0, stream>>>(src, tgt, cursor, srcs, E);

    long long nthreads = (long long)N * 32;
    k_node<<<(int)((nthreads + 255) / 256), 256, 0, stream>>>(
        U, Vb, p, q, offsets, counts, srcs, out, N);
}

// Round 5
// 297.931 us; speedup vs baseline: 2.9980x; 1.0380x over previous
//
#include <hip/hip_runtime.h>

// ---------------------------------------------------------------------------
// GAT edge-average layer, MI355X.
// Phase 0 : k_wconv — Wf (f32) -> W' split-bf16 tables wh/wl [256][128]
// Phase 1 : k_transform — MFMA bf16x3, depth-2 software-pipelined B loads.
//           U[n]=x@Wf1.T, Vb[n]=x@Wf2.T+bf, fused p=x.w1, q=x.w2+bw (f64).
// Phase 2 : CSR build — histogram tgt, 2-level exclusive scan, scatter src
// Phase 3 : k_node — 32 lanes/node, 4-edge unrolled gather, f64 accum.
// ---------------------------------------------------------------------------

typedef short bf16x8 __attribute__((ext_vector_type(8)));
typedef float f32x4  __attribute__((ext_vector_type(4)));

__device__ inline short f32_to_bf16_rne(float f) {
    unsigned u = __float_as_uint(f);
    unsigned r = u + 0x7fffu + ((u >> 16) & 1u);
    return (short)(r >> 16);
}
__device__ inline float bf16s_to_f32(short s) {
    return __uint_as_float(((unsigned)(unsigned short)s) << 16);
}

// W'[c][k]: c<128 -> Wf[c][k] ; c>=128 -> Wf[c-128][128+k]
__global__ __launch_bounds__(256) void k_wconv(
    const float* __restrict__ Wf, short* __restrict__ wh, short* __restrict__ wl)
{
    int i = blockIdx.x * 256 + threadIdx.x;       // 0..32767
    if (i >= 256 * 128) return;
    int c = i >> 7, k = i & 127;
    float v = (c < 128) ? Wf[c * 256 + k] : Wf[(c - 128) * 256 + 128 + k];
    short h = f32_to_bf16_rne(v);
    wh[i] = h;
    wl[i] = f32_to_bf16_rne(v - bf16s_to_f32(h));
}

__global__ __launch_bounds__(256) void k_transform(
    const float* __restrict__ x, const short* __restrict__ wh,
    const short* __restrict__ wl, const float* __restrict__ bf,
    const float* __restrict__ Ww, const float* __restrict__ bw,
    float* __restrict__ U, float* __restrict__ Vb,
    double* __restrict__ p, double* __restrict__ q, int N)
{
    const int wv   = threadIdx.x >> 6;            // wave 0..3
    const int lane = threadIdx.x & 63;
    const int r16  = lane & 15;                   // A-row / C-col within tile
    const int kb   = lane >> 4;                   // k-block (8 elems)
    const int n0   = blockIdx.x * 64 + wv * 16;   // first node of this wave
    const int nrow = n0 + r16;
    const int ncl  = (nrow < N) ? nrow : (N - 1);

    // ---- load this lane's A chunks: 4 k-tiles x 8 f32 at k = kt*32 + kb*8 ----
    float a_f[4][8];
    const float* xr = x + (size_t)ncl * 128 + kb * 8;
    #pragma unroll
    for (int kt = 0; kt < 4; ++kt) {
        f32x4 v0 = *(const f32x4*)(xr + kt * 32);
        f32x4 v1 = *(const f32x4*)(xr + kt * 32 + 4);
        a_f[kt][0] = v0.x; a_f[kt][1] = v0.y; a_f[kt][2] = v0.z; a_f[kt][3] = v0.w;
        a_f[kt][4] = v1.x; a_f[kt][5] = v1.y; a_f[kt][6] = v1.z; a_f[kt][7] = v1.w;
    }

    // ---- preload bias slice for the V half (8 values per lane) ----
    float biasv[8];
    #pragma unroll
    for (int j = 0; j < 8; ++j) biasv[j] = bf[j * 16 + r16];

    // ---- fused p/q (f64), 4 partial chains each ----
    {
        double ps0 = 0.0, ps1 = 0.0, ps2 = 0.0, ps3 = 0.0;
        double qs0 = 0.0, qs1 = 0.0, qs2 = 0.0, qs3 = 0.0;
        #pragma unroll
        for (int kt = 0; kt < 4; ++kt) {
            #pragma unroll
            for (int j = 0; j < 8; j += 4) {
                int k = kt * 32 + kb * 8 + j;
                ps0 += (double)a_f[kt][j + 0] * (double)Ww[k + 0];
                ps1 += (double)a_f[kt][j + 1] * (double)Ww[k + 1];
                ps2 += (double)a_f[kt][j + 2] * (double)Ww[k + 2];
                ps3 += (double)a_f[kt][j + 3] * (double)Ww[k + 3];
                qs0 += (double)a_f[kt][j + 0] * (double)Ww[128 + k + 0];
                qs1 += (double)a_f[kt][j + 1] * (double)Ww[128 + k + 1];
                qs2 += (double)a_f[kt][j + 2] * (double)Ww[128 + k + 2];
                qs3 += (double)a_f[kt][j + 3] * (double)Ww[128 + k + 3];
            }
        }
        double ps = (ps0 + ps1) + (ps2 + ps3);
        double qs = (qs0 + qs1) + (qs2 + qs3);
        ps += __shfl_xor(ps, 16); ps += __shfl_xor(ps, 32);
        qs += __shfl_xor(qs, 16); qs += __shfl_xor(qs, 32);
        if (lane < 16 && nrow < N) {
            p[nrow] = ps;
            q[nrow] = qs + (double)bw[0];
        }
    }

    // ---- convert A to split bf16 fragments ----
    bf16x8 ah[4], al[4];
    #pragma unroll
    for (int kt = 0; kt < 4; ++kt) {
        bf16x8 h, l;
        #pragma unroll
        for (int j = 0; j < 8; ++j) {
            float f = a_f[kt][j];
            short hs = f32_to_bf16_rne(f);
            h[j] = hs;
            l[j] = f32_to_bf16_rne(f - bf16s_to_f32(hs));
        }
        ah[kt] = h; al[kt] = l;
    }

    // ---- 16 col-tiles, depth-2 software-pipelined B loads (3-buffer ring) ----
    bf16x8 BH[3][4], BL[3][4];
    const size_t brow = (size_t)r16 * 128 + kb * 8;

#define LOADB(CT, B) do {                                                     \
    const short* whr_ = wh + (size_t)(CT) * 16 * 128 + brow;                  \
    const short* wlr_ = wl + (size_t)(CT) * 16 * 128 + brow;                  \
    BH[B][0] = *(const bf16x8*)(whr_);       BL[B][0] = *(const bf16x8*)(wlr_);       \
    BH[B][1] = *(const bf16x8*)(whr_ + 32);  BL[B][1] = *(const bf16x8*)(wlr_ + 32);  \
    BH[B][2] = *(const bf16x8*)(whr_ + 64);  BL[B][2] = *(const bf16x8*)(wlr_ + 64);  \
    BH[B][3] = *(const bf16x8*)(whr_ + 96);  BL[B][3] = *(const bf16x8*)(wlr_ + 96);  \
} while (0)

#define STEP(CT, B) do {                                                      \
    f32x4 ac0 = {0.f, 0.f, 0.f, 0.f};                                         \
    f32x4 ac1 = {0.f, 0.f, 0.f, 0.f};                                         \
    ac0 = __builtin_amdgcn_mfma_f32_16x16x32_bf16(ah[0], BH[B][0], ac0, 0,0,0);\
    ac1 = __builtin_amdgcn_mfma_f32_16x16x32_bf16(ah[0], BL[B][0], ac1, 0,0,0);\
    ac0 = __builtin_amdgcn_mfma_f32_16x16x32_bf16(al[0], BH[B][0], ac0, 0,0,0);\
    ac1 = __builtin_amdgcn_mfma_f32_16x16x32_bf16(ah[1], BH[B][1], ac1, 0,0,0);\
    ac0 = __builtin_amdgcn_mfma_f32_16x16x32_bf16(ah[1], BL[B][1], ac0, 0,0,0);\
    ac1 = __builtin_amdgcn_mfma_f32_16x16x32_bf16(al[1], BH[B][1], ac1, 0,0,0);\
    ac0 = __builtin_amdgcn_mfma_f32_16x16x32_bf16(ah[2], BH[B][2], ac0, 0,0,0);\
    ac1 = __builtin_amdgcn_mfma_f32_16x16x32_bf16(ah[2], BL[B][2], ac1, 0,0,0);\
    ac0 = __builtin_amdgcn_mfma_f32_16x16x32_bf16(al[2], BH[B][2], ac0, 0,0,0);\
    ac1 = __builtin_amdgcn_mfma_f32_16x16x32_bf16(ah[3], BH[B][3], ac1, 0,0,0);\
    ac0 = __builtin_amdgcn_mfma_f32_16x16x32_bf16(ah[3], BL[B][3], ac0, 0,0,0);\
    ac1 = __builtin_amdgcn_mfma_f32_16x16x32_bf16(al[3], BH[B][3], ac1, 0,0,0);\
    f32x4 acc;                                                                \
    acc[0] = ac0[0] + ac1[0]; acc[1] = ac0[1] + ac1[1];                       \
    acc[2] = ac0[2] + ac1[2]; acc[3] = ac0[3] + ac1[3];                       \
    if ((CT) < 8) {                                                           \
        int c_ = (CT) * 16 + r16;                                             \
        _Pragma("unroll")                                                     \
        for (int i_ = 0; i_ < 4; ++i_) {                                      \
            int nst_ = n0 + kb * 4 + i_;                                      \
            if (nst_ < N) U[(size_t)nst_ * 128 + c_] = acc[i_];               \
        }                                                                     \
    } else {                                                                  \
        int c_ = ((CT) - 8) * 16 + r16;                                       \
        float bias_ = biasv[(CT) - 8];                                        \
        _Pragma("unroll")                                                     \
        for (int i_ = 0; i_ < 4; ++i_) {                                      \
            int nst_ = n0 + kb * 4 + i_;                                      \
            if (nst_ < N) Vb[(size_t)nst_ * 128 + c_] = acc[i_] + bias_;      \
        }                                                                     \
    }                                                                         \
} while (0)

    LOADB(0, 0); LOADB(1, 1); LOADB(2, 2);
    STEP(0, 0);  LOADB(3, 0);
    STEP(1, 1);  LOADB(4, 1);
    STEP(2, 2);  LOADB(5, 2);
    STEP(3, 0);  LOADB(6, 0);
    STEP(4, 1);  LOADB(7, 1);
    STEP(5, 2);  LOADB(8, 2);
    STEP(6, 0);  LOADB(9, 0);
    STEP(7, 1);  LOADB(10, 1);
    STEP(8, 2);  LOADB(11, 2);
    STEP(9, 0);  LOADB(12, 0);
    STEP(10, 1); LOADB(13, 1);
    STEP(11, 2); LOADB(14, 2);
    STEP(12, 0); LOADB(15, 0);
    STEP(13, 1);
    STEP(14, 2);
    STEP(15, 0);

#undef LOADB
#undef STEP
}

// ---------------- CSR build ----------------

__global__ __launch_bounds__(256) void k_hist(
    const int* __restrict__ tgt, int* __restrict__ counts, int E)
{
    int e = blockIdx.x * 256 + threadIdx.x;
    if (e < E) atomicAdd(&counts[tgt[e]], 1);
}

__global__ __launch_bounds__(256) void k_scan1(
    const int* __restrict__ counts, int* __restrict__ incl,
    int* __restrict__ partials, int N)
{
    __shared__ int sh[256];
    int t = threadIdx.x;
    int i = blockIdx.x * 256 + t;
    int v = (i < N) ? counts[i] : 0;
    sh[t] = v;
    __syncthreads();
    #pragma unroll
    for (int off = 1; off < 256; off <<= 1) {
        int add = (t >= off) ? sh[t - off] : 0;
        __syncthreads();
        sh[t] += add;
        __syncthreads();
    }
    if (i < N) incl[i] = sh[t];
    if (t == 255) partials[blockIdx.x] = sh[255];
}

__global__ __launch_bounds__(256) void k_scan2(int* __restrict__ partials, int nb)
{
    __shared__ int sh[256];
    int t = threadIdx.x;
    int v = (t < nb) ? partials[t] : 0;
    sh[t] = v;
    __syncthreads();
    #pragma unroll
    for (int off = 1; off < 256; off <<= 1) {
        int add = (t >= off) ? sh[t - off] : 0;
        __syncthreads();
        sh[t] += add;
        __syncthreads();
    }
    if (t < nb) partials[t] = sh[t] - v;   // exclusive
}

__global__ __launch_bounds__(256) void k_scan3(
    const int* __restrict__ counts, const int* __restrict__ incl,
    const int* __restrict__ partials, int* __restrict__ offsets,
    int* __restrict__ cursor, int N)
{
    int i = blockIdx.x * 256 + threadIdx.x;
    if (i >= N) return;
    int off = incl[i] - counts[i] + partials[i >> 8];
    offsets[i] = off;
    cursor[i]  = off;
}

__global__ __launch_bounds__(256) void k_scatter(
    const int* __restrict__ src, const int* __restrict__ tgt,
    int* __restrict__ cursor, int* __restrict__ srcs, int E)
{
    int e = blockIdx.x * 256 + threadIdx.x;
    if (e >= E) return;
    int pos = atomicAdd(&cursor[tgt[e]], 1);
    srcs[pos] = src[e];
}

// ------------- node aggregation: 32 lanes/node, 4-edge pipeline -------------

__global__ __launch_bounds__(256) void k_node(
    const float* __restrict__ U, const float* __restrict__ Vb,
    const double* __restrict__ p, const double* __restrict__ q,
    const int* __restrict__ offsets, const int* __restrict__ counts,
    const int* __restrict__ srcs, float* __restrict__ out, int N)
{
    int idx  = blockIdx.x * 256 + threadIdx.x;
    int n    = idx >> 5;                 // 32 lanes per node
    int lane = threadIdx.x & 31;
    if (n >= N) return;

    float4 Vn = ((const float4*)(Vb + (size_t)n * 128))[lane];
    double qn = q[n];                    // includes bw
    int beg = offsets[n];
    int cnt = counts[n];

    double ax = 0.0, ay = 0.0, az = 0.0, aw = 0.0, asum = 0.0;

    int i = 0;
    for (; i + 4 <= cnt; i += 4) {
        int s0 = srcs[beg + i + 0];
        int s1 = srcs[beg + i + 1];
        int s2 = srcs[beg + i + 2];
        int s3 = srcs[beg + i + 3];
        float4 U0 = ((const float4*)(U + (size_t)s0 * 128))[lane];
        float4 U1 = ((const float4*)(U + (size_t)s1 * 128))[lane];
        float4 U2 = ((const float4*)(U + (size_t)s2 * 128))[lane];
        float4 U3 = ((const float4*)(U + (size_t)s3 * 128))[lane];
        double a0 = p[s0] + qn, a1 = p[s1] + qn, a2 = p[s2] + qn, a3 = p[s3] + qn;
        float f0 = (float)a0, f1 = (float)a1, f2 = (float)a2, f3 = (float)a3;

        ax += (double)(fmaxf(U0.x + Vn.x, 0.f) * f0);
        ay += (double)(fmaxf(U0.y + Vn.y, 0.f) * f0);
        az += (double)(fmaxf(U0.z + Vn.z, 0.f) * f0);
        aw += (double)(fmaxf(U0.w + Vn.w, 0.f) * f0);
        asum += a0;
        ax += (double)(fmaxf(U1.x + Vn.x, 0.f) * f1);
        ay += (double)(fmaxf(U1.y + Vn.y, 0.f) * f1);
        az += (double)(fmaxf(U1.z + Vn.z, 0.f) * f1);
        aw += (double)(fmaxf(U1.w + Vn.w, 0.f) * f1);
        asum += a1;
        ax += (double)(fmaxf(U2.x + Vn.x, 0.f) * f2);
        ay += (double)(fmaxf(U2.y + Vn.y, 0.f) * f2);
        az += (double)(fmaxf(U2.z + Vn.z, 0.f) * f2);
        aw += (double)(fmaxf(U2.w + Vn.w, 0.f) * f2);
        asum += a2;
        ax += (double)(fmaxf(U3.x + Vn.x, 0.f) * f3);
        ay += (double)(fmaxf(U3.y + Vn.y, 0.f) * f3);
        az += (double)(fmaxf(U3.z + Vn.z, 0.f) * f3);
        aw += (double)(fmaxf(U3.w + Vn.w, 0.f) * f3);
        asum += a3;
    }
    for (; i < cnt; ++i) {
        int s = srcs[beg + i];
        float4 Ue = ((const float4*)(U + (size_t)s * 128))[lane];
        double a = p[s] + qn;
        float af = (float)a;
        ax += (double)(fmaxf(Ue.x + Vn.x, 0.f) * af);
        ay += (double)(fmaxf(Ue.y + Vn.y, 0.f) * af);
        az += (double)(fmaxf(Ue.z + Vn.z, 0.f) * af);
        aw += (double)(fmaxf(Ue.w + Vn.w, 0.f) * af);
        asum += a;
    }

    double inv = 1.0 / (asum + 1e-6);
    float4 o;
    o.x = (float)(ax * inv);
    o.y = (float)(ay * inv);
    o.z = (float)(az * inv);
    o.w = (float)(aw * inv);
    ((float4*)(out + (size_t)n * 128))[lane] = o;
}

extern "C" void kernel_launch(void* const* d_in, const int* in_sizes, int n_in,
                              void* d_out, int out_size, void* d_ws, size_t ws_size,
                              hipStream_t stream)
{
    const float* x   = (const float*)d_in[0];
    const float* Wf  = (const float*)d_in[1];
    const float* bf  = (const float*)d_in[2];
    const float* Ww  = (const float*)d_in[3];
    const float* bw  = (const float*)d_in[4];
    const int*   src = (const int*)d_in[5];
    const int*   tgt = (const int*)d_in[6];

    const int N = in_sizes[0] / 128;
    const int E = in_sizes[5];
    float* out = (float*)d_out;

    // workspace layout
    char* w = (char*)d_ws;
    float*  U        = (float*)w;                 w += (size_t)N * 128 * sizeof(float);
    float*  Vb       = (float*)w;                 w += (size_t)N * 128 * sizeof(float);
    double* p        = (double*)w;                w += (size_t)N * sizeof(double);
    double* q        = (double*)w;                w += (size_t)N * sizeof(double);
    int*    counts   = (int*)w;                   w += (size_t)N * sizeof(int);
    int*    incl     = (int*)w;                   w += (size_t)N * sizeof(int);
    int*    offsets  = (int*)w;                   w += (size_t)N * sizeof(int);
    int*    cursor   = (int*)w;                   w += (size_t)N * sizeof(int);
    int*    partials = (int*)w;                   w += 4096;
    int*    srcs     = (int*)w;                   w += (size_t)E * sizeof(int);
    short*  wh       = (short*)w;                 w += 256 * 128 * sizeof(short);
    short*  wl       = (short*)w;

    hipMemsetAsync(counts, 0, (size_t)N * sizeof(int), stream);

    k_wconv<<<128, 256, 0, stream>>>(Wf, wh, wl);
    k_transform<<<(N + 63) / 64, 256, 0, stream>>>(
        x, wh, wl, bf, Ww, bw, U, Vb, p, q, N);

    int ebk = (E + 255) / 256;
    int nbk = (N + 255) / 256;
    k_hist<<<ebk, 256, 0, stream>>>(tgt, counts, E);
    k_scan1<<<nbk, 256, 0, stream>>>(counts, incl, partials, N);
    k_scan2<<<1, 256, 0, stream>>>(partials, nbk);
    k_scan3<<<nbk, 256, 0, stream>>>(counts, incl, partials, offsets, cursor, N);
    k_scatter<<<ebk, 256, 0, stream>>>(src, tgt, cursor, srcs, E);

    long long nthreads = (long long)N * 32;
    k_node<<<(int)((nthreads + 255) / 256), 256, 0, stream>>>(
        U, Vb, p, q, offsets, counts, srcs, out, N);
}